// Round 2
// baseline (304.178 us; speedup 1.0000x reference)
//
#include <hip/hip_runtime.h>

// x[B=16,C=64,H=224,W=224] fp32, dct_bases[M=16,16,16] fp32 -> out[B,M,H,W] fp32.
#define B_   16
#define C_   64
#define H_   224
#define W_   224
#define M_   16
#define PH   16
#define PW   16
#define HP   14                    // H/PH
#define WP   14                    // W/PW
#define PLANE (H_ * W_)            // 50176 floats per (b,c) plane
#define PLANE4 (PLANE / 4)         // 12544 float4 per plane
#define NCOEF (B_ * M_ * HP * WP)  // 50176 coeffs

// ---------------- K1: channel mean, fully-coalesced streaming read ----------------
// grid: (PLANE4/256, B_) ; thread handles one float4 of mean[b], loops 64 channels.
__global__ __launch_bounds__(256)
void k1_mean(const float* __restrict__ x, float* __restrict__ mean) {
    const int f4 = blockIdx.x * 256 + threadIdx.x;   // 0..PLANE4-1
    const int b  = blockIdx.y;
    const float4* p = (const float4*)x + (size_t)b * C_ * PLANE4 + f4;
    float4 acc = {0.f, 0.f, 0.f, 0.f};
#pragma unroll 16
    for (int c = 0; c < C_; ++c) {
        float4 v = p[(size_t)c * PLANE4];
        acc.x += v.x; acc.y += v.y; acc.z += v.z; acc.w += v.w;
    }
    const float inv = 1.f / (float)C_;
    acc.x *= inv; acc.y *= inv; acc.z *= inv; acc.w *= inv;
    ((float4*)mean)[(size_t)b * PLANE4 + f4] = acc;
}

// ---------------- K2a: per-patch DCT coefficients ----------------
// grid: (HP*WP, B_), 256 threads. coeff layout [b][m][hp][wp].
__global__ __launch_bounds__(256)
void k2a_coeff(const float* __restrict__ mean, const float* __restrict__ bases,
               float* __restrict__ coeff) {
    const int pid = blockIdx.x;          // 0..HP*WP-1
    const int wp  = pid % WP;
    const int hp  = pid / WP;
    const int b   = blockIdx.y;

    __shared__ float patch[PH * 20];     // row stride 20 (float4-aligned, bank-safe)

    const int t = threadIdx.x;
    if (t < 64) {
        const int i  = t >> 2;           // patch row
        const int c4 = t & 3;            // float4 col group
        const float4 v = *(const float4*)(mean + (size_t)b * PLANE
                                          + (size_t)(hp * PH + i) * W_
                                          + wp * PW + c4 * 4);
        *(float4*)&patch[i * 20 + c4 * 4] = v;
    }
    __syncthreads();

    const int m = t >> 4;                // basis 0..15
    const int s = t & 15;                // patch row 0..15
    const float* brow = bases + m * (PH * PW) + s * PW;
    float partial = 0.f;
#pragma unroll
    for (int k = 0; k < 16; ++k)
        partial += patch[s * 20 + k] * brow[k];
    partial += __shfl_xor(partial, 1);
    partial += __shfl_xor(partial, 2);
    partial += __shfl_xor(partial, 4);
    partial += __shfl_xor(partial, 8);
    if (s == 0)
        coeff[(((size_t)b * M_ + m) * HP + hp) * WP + wp] = partial;
}

// ---------------- K2b: nearest-upsample broadcast, pure coalesced write ----------------
// grid: (PLANE4/256, B_*M_), 256 threads; each thread writes one float4 of out.
__global__ __launch_bounds__(256)
void k2b_broadcast(const float* __restrict__ coeff, float* __restrict__ out) {
    const int o4 = blockIdx.x * 256 + threadIdx.x;   // 0..PLANE4-1 within plane
    const int bm = blockIdx.y;                        // b*M_ + m
    const int w4 = o4 % (W_ / 4);                     // 0..55
    const int h  = o4 / (W_ / 4);                     // 0..223
    const int hp = h >> 4;
    const int wp = w4 >> 2;                           // (w4*4)/16
    const float c = coeff[((size_t)bm * HP + hp) * WP + wp];
    float4 v = {c, c, c, c};
    ((float4*)out)[(size_t)bm * PLANE4 + o4] = v;
}

extern "C" void kernel_launch(void* const* d_in, const int* in_sizes, int n_in,
                              void* d_out, int out_size, void* d_ws, size_t ws_size,
                              hipStream_t stream) {
    const float* x     = (const float*)d_in[0];
    const float* bases = (const float*)d_in[1];
    float* out         = (float*)d_out;

    float* mean  = (float*)d_ws;                     // B_*PLANE floats = 3.2 MB
    float* coeff = mean + (size_t)B_ * PLANE;        // NCOEF floats = 200 KB

    dim3 g1(PLANE4 / 256, B_);        // 49 x 16 = 784 blocks
    k1_mean<<<g1, 256, 0, stream>>>(x, mean);

    dim3 g2(HP * WP, B_);             // 196 x 16 = 3136 blocks
    k2a_coeff<<<g2, 256, 0, stream>>>(mean, bases, coeff);

    dim3 g3(PLANE4 / 256, B_ * M_);   // 49 x 256 = 12544 blocks
    k2b_broadcast<<<g3, 256, 0, stream>>>(coeff, out);
}

// Round 3
// 302.357 us; speedup vs baseline: 1.0060x; 1.0060x over previous
//
#include <hip/hip_runtime.h>

// x[B=16,C=64,H=224,W=224] fp32, dct_bases[M=16,16,16] fp32 -> out[B,M,H,W] fp32.
#define B_   16
#define C_   64
#define H_   224
#define W_   224
#define M_   16
#define PH   16
#define PW   16
#define HP   14                    // H/PH
#define WP   14                    // W/PW
#define PLANE (H_ * W_)            // 50176 floats per (b,c) plane
#define PLANE4 (PLANE / 4)         // 12544 float4 per plane
#define BAND  (PH * W_)            // 3584 floats per (b,hp) row-band
#define BAND4 (BAND / 4)           // 896 float4 per band
#define LSTRIDE 228                // LDS row stride: 228%32=4 -> only 2-way bank alias (free)

// ---------------- K1: channel mean, fully-coalesced streaming read ----------------
// grid: (PLANE4/256, B_); thread handles one float4 of mean[b], loops 64 channels.
__global__ __launch_bounds__(256)
void k1_mean(const float* __restrict__ x, float* __restrict__ mean) {
    const int f4 = blockIdx.x * 256 + threadIdx.x;   // 0..PLANE4-1
    const int b  = blockIdx.y;
    const float4* p = (const float4*)x + (size_t)b * C_ * PLANE4 + f4;
    float4 acc = {0.f, 0.f, 0.f, 0.f};
#pragma unroll 16
    for (int c = 0; c < C_; ++c) {
        float4 v = p[(size_t)c * PLANE4];
        acc.x += v.x; acc.y += v.y; acc.z += v.z; acc.w += v.w;
    }
    const float inv = 1.f / (float)C_;
    acc.x *= inv; acc.y *= inv; acc.z *= inv; acc.w *= inv;
    ((float4*)mean)[(size_t)b * PLANE4 + f4] = acc;
}

// ---------------- K2: fused DCT-project + broadcast-write ----------------
// grid: (M_, HP, B_) = 3584 blocks, 256 threads.
// Block (m, hp, b): loads the (b,hp) mean band (16 rows x 224) into LDS,
// computes coeff[wp] for its basis m across wp=0..13, then writes its
// contiguous output band out[b][m][hp*16:+16][:] with 1 KB/wave stores.
__global__ __launch_bounds__(256)
void k2_dct_write(const float* __restrict__ mean, const float* __restrict__ bases,
                  float* __restrict__ out) {
    const int m  = blockIdx.x;
    const int hp = blockIdx.y;
    const int b  = blockIdx.z;
    const int t  = threadIdx.x;

    __shared__ float band[PH * LSTRIDE];   // 16 x 228 = 14.6 KB
    __shared__ float cf[WP];               // 14 coefficients

    // Phase 1: coalesced load of the mean band into LDS.
    const float4* src = (const float4*)(mean + (size_t)b * PLANE + (size_t)hp * BAND);
    for (int j = t; j < BAND4; j += 256) {
        const int row  = j / (W_ / 4);     // 0..15
        const int col4 = j % (W_ / 4);     // 0..55
        *(float4*)&band[row * LSTRIDE + col4 * 4] = src[j];
    }
    __syncthreads();

    // Phase 2: 14 dot products (one per wp) for basis m.
    // thread t < 224: wp = t>>4, s = t&15; partial over row s's 16 cols.
    if (t < WP * 16) {
        const int wp = t >> 4;
        const int s  = t & 15;
        const float* brow = bases + m * (PH * PW) + s * PW;
        float partial = 0.f;
#pragma unroll
        for (int k = 0; k < 16; ++k)
            partial += band[s * LSTRIDE + wp * PW + k] * brow[k];
        partial += __shfl_xor(partial, 1);
        partial += __shfl_xor(partial, 2);
        partial += __shfl_xor(partial, 4);
        partial += __shfl_xor(partial, 8);
        if (s == 0) cf[wp] = partial;
    }
    __syncthreads();

    // Phase 3: contiguous broadcast-write of the output band (896 float4).
    float4* dst = (float4*)(out + ((size_t)b * M_ + m) * PLANE + (size_t)hp * BAND);
#pragma unroll
    for (int j4 = 0; j4 < BAND4; j4 += 256) {
        const int j    = j4 + t;
        const int col4 = j % (W_ / 4);     // 0..55
        if (j < BAND4) {
            const float c = cf[col4 >> 2]; // wp = (col4*4)/16
            float4 v = {c, c, c, c};
            dst[j] = v;
        }
    }
}

extern "C" void kernel_launch(void* const* d_in, const int* in_sizes, int n_in,
                              void* d_out, int out_size, void* d_ws, size_t ws_size,
                              hipStream_t stream) {
    const float* x     = (const float*)d_in[0];
    const float* bases = (const float*)d_in[1];
    float* out         = (float*)d_out;

    float* mean = (float*)d_ws;            // B_*PLANE floats = 3.2 MB

    dim3 g1(PLANE4 / 256, B_);             // 49 x 16 = 784 blocks
    k1_mean<<<g1, 256, 0, stream>>>(x, mean);

    dim3 g2(M_, HP, B_);                   // 16 x 14 x 16 = 3584 blocks
    k2_dct_write<<<g2, 256, 0, stream>>>(mean, bases, out);
}